// Round 11
// baseline (160.023 us; speedup 1.0000x reference)
//
#include <hip/hip_runtime.h>
#include <cstdint>
#include <cstddef>

#define H 512
#define SEQ 128

typedef __bf16 v8bf __attribute__((ext_vector_type(8)));
typedef float v4f __attribute__((ext_vector_type(4)));
typedef unsigned short v8us __attribute__((ext_vector_type(8)));

__device__ __forceinline__ unsigned short f2bf(float f) {
    unsigned int u = __float_as_uint(f);
    u = (u + 0x7FFFu + ((u >> 16) & 1u)) >> 16;
    return (unsigned short)u;
}
__device__ __forceinline__ float bf2f(unsigned short h) {
    return __uint_as_float(((unsigned int)h) << 16);
}
__device__ __forceinline__ v8bf load_bf8(const unsigned short* p) {
    return *reinterpret_cast<const v8bf*>(p);
}
__device__ __forceinline__ float fast_tanh(float v) {
    float e = __expf(2.f * v);
    return 1.f - 2.f * __builtin_amdgcn_rcpf(e + 1.f);
}
__device__ __forceinline__ float fast_sigmoid(float v) {
    return __builtin_amdgcn_rcpf(1.f + __expf(-v));
}
__device__ __forceinline__ v8us cvt8u(float4 lo, float4 hi) {
    v8us r;
    r[0] = f2bf(lo.x); r[1] = f2bf(lo.y); r[2] = f2bf(lo.z); r[3] = f2bf(lo.w);
    r[4] = f2bf(hi.x); r[5] = f2bf(hi.y); r[6] = f2bf(hi.z); r[7] = f2bf(hi.w);
    return r;
}

// Swizzled B layout: frag[((c*16 + ks)*64 + lane)*8 + j] = W[g][k]
//   g = c*16 + (lane&15),  k = ks*32 + (lane>>4)*8 + j

// ---------------------------------------------------------------------------
// prep: build swizzled WyS (Wl[:, :512]), WiS (Wl[:, 512:]), WaS (Wa1^T)
// ---------------------------------------------------------------------------
__global__ __launch_bounds__(256) void prep_kernel(
        const float* __restrict__ Wa1, const float* __restrict__ Wl,
        unsigned short* __restrict__ WyS, unsigned short* __restrict__ WiS,
        unsigned short* __restrict__ WaS) {
    int tg = blockIdx.x * 256 + threadIdx.x;   // 0..98303
    int mat = tg >> 15;
    int idx = tg & 32767;
    int lane = idx & 63;
    int ks = (idx >> 6) & 15;
    int c = idx >> 10;
    int g = c * 16 + (lane & 15);
    int hb = ks * 32 + ((lane >> 4) << 3);
    unsigned short o[8];
    unsigned short* dst;
    if (mat == 0) {
        const float* s = Wl + (size_t)g * 1024 + hb;
#pragma unroll
        for (int j = 0; j < 8; ++j) o[j] = f2bf(s[j]);
        dst = WyS + (size_t)idx * 8;
    } else if (mat == 1) {
        const float* s = Wl + (size_t)g * 1024 + 512 + hb;
#pragma unroll
        for (int j = 0; j < 8; ++j) o[j] = f2bf(s[j]);
        dst = WiS + (size_t)idx * 8;
    } else {
#pragma unroll
        for (int j = 0; j < 8; ++j) o[j] = f2bf(Wa1[(size_t)(hb + j) * H + g]);
        dst = WaS + (size_t)idx * 8;
    }
    *reinterpret_cast<ushort4*>(dst)     = *reinterpret_cast<ushort4*>(&o[0]);
    *reinterpret_cast<ushort4*>(dst + 4) = *reinterpret_cast<ushort4*>(&o[4]);
}

// ---------------------------------------------------------------------------
// attn_pool: one block per (b, s<127).  wave = 32 rows x 128 cols, acc 2x8.
// ---------------------------------------------------------------------------
__global__ __launch_bounds__(256, 4) void attn_pool_kernel(
        const float* __restrict__ x, const unsigned short* __restrict__ WaS,
        const float* __restrict__ ba1, const float* __restrict__ wa2,
        float* __restrict__ ixf, unsigned short* __restrict__ ixb) {
    __shared__ __align__(16) unsigned short Xb[32][520];
    __shared__ float attn[32];
    __shared__ float scpart[4][32];

    int bid = blockIdx.x;
    int b = bid / 127, s = bid % 127;
    int t = threadIdx.x;

    const float4* x4 = reinterpret_cast<const float4*>(x + (size_t)(b * SEQ + s) * 32 * H);
#pragma unroll
    for (int i = 0; i < 16; ++i) {
        int idx4 = t + i * 256;
        float4 v = x4[idx4];
        int e = idx4 * 4, m = e >> 9, h = e & 511;
        ushort4 o;
        o.x = f2bf(v.x); o.y = f2bf(v.y); o.z = f2bf(v.z); o.w = f2bf(v.w);
        *reinterpret_cast<ushort4*>(&Xb[m][h]) = o;
    }
    __syncthreads();

    int w = t >> 6, lane = t & 63, q = lane >> 4, c16 = lane & 15;

    v4f acc[2][8];
#pragma unroll
    for (int mi = 0; mi < 2; ++mi)
#pragma unroll
        for (int ci = 0; ci < 8; ++ci) acc[mi][ci] = (v4f){0.f, 0.f, 0.f, 0.f};

    const unsigned short* Bb = WaS + (size_t)(w * 8 * 16) * 512 + lane * 8;

#pragma unroll
    for (int ks = 0; ks < 16; ++ks) {
        v8bf a0 = load_bf8(&Xb[c16][ks * 32 + q * 8]);
        v8bf a1 = load_bf8(&Xb[16 + c16][ks * 32 + q * 8]);
#pragma unroll
        for (int ci = 0; ci < 8; ++ci) {
            v8bf bb = load_bf8(Bb + (size_t)(ci * 16 + ks) * 512);
            acc[0][ci] = __builtin_amdgcn_mfma_f32_16x16x32_bf16(a0, bb, acc[0][ci], 0, 0, 0);
            acc[1][ci] = __builtin_amdgcn_mfma_f32_16x16x32_bf16(a1, bb, acc[1][ci], 0, 0, 0);
        }
    }

    float sr[2][4] = {{0.f, 0.f, 0.f, 0.f}, {0.f, 0.f, 0.f, 0.f}};
#pragma unroll
    for (int ci = 0; ci < 8; ++ci) {
        int g = (w * 8 + ci) * 16 + c16;
        float w2 = wa2[g];
        float bv = ba1[g];
#pragma unroll
        for (int mi = 0; mi < 2; ++mi)
#pragma unroll
            for (int i = 0; i < 4; ++i)
                sr[mi][i] += w2 * fast_tanh(acc[mi][ci][i] + bv);
    }
#pragma unroll
    for (int off = 1; off < 16; off <<= 1) {
#pragma unroll
        for (int mi = 0; mi < 2; ++mi)
#pragma unroll
            for (int i = 0; i < 4; ++i) sr[mi][i] += __shfl_xor(sr[mi][i], off);
    }
    if (c16 == 0) {
#pragma unroll
        for (int mi = 0; mi < 2; ++mi)
#pragma unroll
            for (int i = 0; i < 4; ++i) scpart[w][mi * 16 + q * 4 + i] = sr[mi][i];
    }
    __syncthreads();

    if (t < 64) {
        int m = t & 31;
        float v = scpart[0][m] + scpart[1][m] + scpart[2][m] + scpart[3][m];
        float mx = v;
#pragma unroll
        for (int off = 1; off < 32; off <<= 1) mx = fmaxf(mx, __shfl_xor(mx, off));
        float e = __expf(v - mx);
        float sum = e;
#pragma unroll
        for (int off = 1; off < 32; off <<= 1) sum += __shfl_xor(sum, off);
        if (t < 32) attn[m] = e * __builtin_amdgcn_rcpf(sum);
    }
    __syncthreads();

    int h0 = t * 2;
    float p0 = 0.f, p1 = 0.f;
#pragma unroll
    for (int m = 0; m < 32; ++m) {
        float am = attn[m];
        p0 += am * bf2f(Xb[m][h0]);
        p1 += am * bf2f(Xb[m][h0 + 1]);
    }
    size_t r = (size_t)bid;
    ixf[r * H + h0] = p0;
    ixf[r * H + h0 + 1] = p1;
    ixb[r * H + h0] = f2bf(p0);
    ixb[r * H + h0 + 1] = f2bf(p1);
}

// ---------------------------------------------------------------------------
// ipre: i_pre[r,g] = sum_h i_x[r,h] * Wi[g,h] + bl[g]   (r < 1016)
// ---------------------------------------------------------------------------
__global__ __launch_bounds__(256) void ipre_kernel(
        const unsigned short* __restrict__ ixb, const unsigned short* __restrict__ WiS,
        const float* __restrict__ bl, float* __restrict__ ipre) {
    int row16 = blockIdx.x * 16;
    int t = threadIdx.x, w = t >> 6, lane = t & 63, q = lane >> 4, c16 = lane & 15;
    int c0 = blockIdx.y * 8 + w * 2;

    v4f acc0 = {0.f, 0.f, 0.f, 0.f};
    v4f acc1 = {0.f, 0.f, 0.f, 0.f};
    const unsigned short* arow = ixb + (size_t)(row16 + c16) * H + q * 8;
#pragma unroll
    for (int ks = 0; ks < 16; ++ks) {
        v8bf a = load_bf8(arow + ks * 32);
        acc0 = __builtin_amdgcn_mfma_f32_16x16x32_bf16(
            a, load_bf8(WiS + (size_t)(c0 * 16 + ks) * 512 + lane * 8), acc0, 0, 0, 0);
        acc1 = __builtin_amdgcn_mfma_f32_16x16x32_bf16(
            a, load_bf8(WiS + (size_t)((c0 + 1) * 16 + ks) * 512 + lane * 8), acc1, 0, 0, 0);
    }
#pragma unroll
    for (int cc = 0; cc < 2; ++cc) {
        int g = (c0 + cc) * 16 + c16;
        float blv = bl[g];
        v4f a = cc ? acc1 : acc0;
#pragma unroll
        for (int i = 0; i < 4; ++i) {
            int row = row16 + q * 4 + i;
            if (row < 1016) ipre[(size_t)row * H + g] = a[i] + blv;
        }
    }
}

// ---------------------------------------------------------------------------
// main v11: 256x256 block (4 tiles x col-half), wave = 64 rows x 128 cols,
// acc[4][8] = 128 AGPR.  LDS-reads-per-output drops 3.3x (12 reads feed 32
// MFMAs/wave/phase); B L3 traffic halves; 508 GEMM blocks ~ 2/CU serial.
// K: 16 phases, dbuf, reg-staged A (f32->bf16) + B, one barrier/phase.
// Coalesced LDS epilogue (8 slabs of 32 rows), bijective XCD swizzle (508=8q+4).
// LDS 80 KB; launch_bounds(512,2) -> 256-reg cap, 1 block/CU (ILP over TLP).
// ---------------------------------------------------------------------------
__global__ __launch_bounds__(512, 2) void main_kernel(
        const float* __restrict__ y, const unsigned short* __restrict__ WyS,
        const float* __restrict__ ixf, const float* __restrict__ ipre,
        float* __restrict__ out) {
    int bid0 = blockIdx.x;
    int t = threadIdx.x;

    if (bid0 >= 508) {
        // s==0 passthrough: 16 blocks, each copies 32 rows x 512 cols f32.
        int cb = bid0 - 508;             // 0..15
        int b = cb >> 1, half = cb & 1;
        size_t base = ((size_t)(b * SEQ)) * 64 * H + (size_t)half * 32 * H;
        const float4* y4 = reinterpret_cast<const float4*>(y + base);
        float4* o4 = reinterpret_cast<float4*>(out + base);
#pragma unroll
        for (int i = 0; i < 8; ++i) o4[t + i * 512] = y4[t + i * 512];
        return;
    }

    // bijective XCD swizzle: 508 = 8*63 + 4 (m204 formula, q=63, r=4)
    int xcd = bid0 & 7, sid = bid0 >> 3;
    int bid = (xcd < 4 ? xcd * 64 : 256 + (xcd - 4) * 63) + sid;

    int rg = bid >> 1;                   // 0..253: rows 256 = tiles 4rg..4rg+3
    int ch = bid & 1;                    // col half: g in [ch*256, ch*256+256)

    __shared__ __align__(16) char arena[81920];
    unsigned short* As = (unsigned short*)arena;              // [2][256*40] bf16
    unsigned short* Bs = (unsigned short*)(arena + 40960);    // [2][16*512] bf16
    float* ip_s = (float*)(arena + 73728);                    // [4*256]
    float* ix_s = (float*)(arena + 77824);                    // [4*256]
    float* ep   = (float*)arena;                              // epilogue alias [32][260]

    int t0 = rg * 4;

    // ---- A staging assignment: thread -> row t>>1, col-half (t&1)*16 ----
    int arow = t >> 1;                   // 0..255
    int acol = (t & 1) * 16;
    int atile = t0 + (arow >> 6);
    int aab = atile / 127, aas = atile % 127;
    const float* ysrc = y + ((size_t)(aab * SEQ + aas + 1) * 64 + (arow & 63)) * H;

    // ---- B staging assignment: frag f = t>>5, 32B at (t&31)*16 ----
    int bfr = t >> 5;                    // 0..15
    int boff = (t & 31) * 16;
    const unsigned short* bsrc = WyS + ((size_t)((ch * 16 + bfr) * 16)) * 512 + boff;

    int w = t >> 6, lane = t & 63, q = lane >> 4, c16 = lane & 15;
    int wr = w >> 1, wc = w & 1;

    // ---- ip/ix staging: 1024 entries = 4 tiles x 256 cols ----
#pragma unroll
    for (int j = 0; j < 2; ++j) {
        int e = t + j * 512;
        int ti = e >> 8, gl = e & 255;
        size_t rr = (size_t)(t0 + ti) * H + ch * 256 + gl;
        ip_s[e] = ipre[rr];
        ix_s[e] = ixf[rr];
    }

    // ---- prologue: stage phase 0 ----
    {
        float4 a0 = *reinterpret_cast<const float4*>(ysrc + acol);
        float4 a1 = *reinterpret_cast<const float4*>(ysrc + acol + 4);
        float4 a2 = *reinterpret_cast<const float4*>(ysrc + acol + 8);
        float4 a3 = *reinterpret_cast<const float4*>(ysrc + acol + 12);
        v8us b0 = *reinterpret_cast<const v8us*>(bsrc);
        v8us b1 = *reinterpret_cast<const v8us*>(bsrc + 8);
        *reinterpret_cast<v8us*>(&As[arow * 40 + acol])     = cvt8u(a0, a1);
        *reinterpret_cast<v8us*>(&As[arow * 40 + acol + 8]) = cvt8u(a2, a3);
        *reinterpret_cast<v8us*>(&Bs[bfr * 512 + boff])     = b0;
        *reinterpret_cast<v8us*>(&Bs[bfr * 512 + boff + 8]) = b1;
    }
    __syncthreads();

    v4f acc[4][8];
#pragma unroll
    for (int rt = 0; rt < 4; ++rt)
#pragma unroll
        for (int ci = 0; ci < 8; ++ci) acc[rt][ci] = (v4f){0.f, 0.f, 0.f, 0.f};

    // ---- main K loop: 16 phases, dbuf, issue-early / write-late ----
#pragma unroll
    for (int p = 0; p < 16; ++p) {
        const int cur = p & 1;
        float4 a0, a1, a2, a3; v8us b0, b1;
        if (p < 15) {
            const float* ap = ysrc + (p + 1) * 32 + acol;
            a0 = *reinterpret_cast<const float4*>(ap);
            a1 = *reinterpret_cast<const float4*>(ap + 4);
            a2 = *reinterpret_cast<const float4*>(ap + 8);
            a3 = *reinterpret_cast<const float4*>(ap + 12);
            b0 = *reinterpret_cast<const v8us*>(bsrc + (p + 1) * 512);
            b1 = *reinterpret_cast<const v8us*>(bsrc + (p + 1) * 512 + 8);
        }

        v8bf af[4];
#pragma unroll
        for (int rt = 0; rt < 4; ++rt)
            af[rt] = load_bf8(&As[cur * 10240 + (wr * 64 + rt * 16 + c16) * 40 + q * 8]);
#pragma unroll
        for (int ci = 0; ci < 8; ++ci) {
            v8bf bfc = load_bf8(&Bs[cur * 8192 + (wc * 8 + ci) * 512 + lane * 8]);
#pragma unroll
            for (int rt = 0; rt < 4; ++rt)
                acc[rt][ci] = __builtin_amdgcn_mfma_f32_16x16x32_bf16(
                    af[rt], bfc, acc[rt][ci], 0, 0, 0);
        }

        if (p < 15) {
            const int nxt = cur ^ 1;
            *reinterpret_cast<v8us*>(&As[nxt * 10240 + arow * 40 + acol])     = cvt8u(a0, a1);
            *reinterpret_cast<v8us*>(&As[nxt * 10240 + arow * 40 + acol + 8]) = cvt8u(a2, a3);
            *reinterpret_cast<v8us*>(&Bs[nxt * 8192 + bfr * 512 + boff])      = b0;
            *reinterpret_cast<v8us*>(&Bs[nxt * 8192 + bfr * 512 + boff + 8])  = b1;
            __syncthreads();
        }
    }

    // ---- coalesced epilogue via LDS, 8 slabs of 32 rows ----
#pragma unroll
    for (int s = 0; s < 8; ++s) {
        __syncthreads();   // s=0: also protects As/Bs (aliased by ep) from K-loop
        if (wr == (s >> 1)) {
            const int rh = s & 1;
#pragma unroll
            for (int ci = 0; ci < 8; ++ci) {
                int gl = wc * 128 + ci * 16 + c16;        // 0..255
                float ipv = ip_s[(s >> 1) * 256 + gl];
                float ixv = ix_s[(s >> 1) * 256 + gl];
#pragma unroll
                for (int rtl = 0; rtl < 2; ++rtl) {
                    const int rt = rh * 2 + rtl;
#pragma unroll
                    for (int i = 0; i < 4; ++i) {
                        int rl = rtl * 16 + q * 4 + i;    // 0..31 within slab
                        ep[rl * 260 + gl] = ixv * fast_sigmoid(acc[rt][ci][i] + ipv);
                    }
                }
            }
        }
        __syncthreads();
        // slab's output tile is constant: tile = t0 + (s>>1), rows (s&1)*32..+32
        int tile = t0 + (s >> 1);
        int ab2 = tile / 127, as2 = tile % 127;
        size_t obase = ((size_t)(ab2 * SEQ + as2 + 1) * 64) * H;
#pragma unroll
        for (int k = 0; k < 4; ++k) {
            int c = t + k * 512;                  // 0..2047
            int rl = c >> 6;                      // 0..31
            int cx = (c & 63) * 4;                // f32 col within 256
            int n = (s & 1) * 32 + rl;            // row within tile
            size_t off = obase + (size_t)n * H + ch * 256 + cx;
            float4 g4 = *reinterpret_cast<const float4*>(&ep[rl * 260 + cx]);
            float4 yv = *reinterpret_cast<const float4*>(&y[off]);
            float4 o;
            o.x = yv.x + g4.x; o.y = yv.y + g4.y;
            o.z = yv.z + g4.z; o.w = yv.w + g4.w;
            *reinterpret_cast<float4*>(&out[off]) = o;
        }
    }
}

// ---------------------------------------------------------------------------
extern "C" void kernel_launch(void* const* d_in, const int* in_sizes, int n_in,
                              void* d_out, int out_size, void* d_ws, size_t ws_size,
                              hipStream_t stream) {
    const float* x   = (const float*)d_in[0];
    const float* y   = (const float*)d_in[1];
    const float* Wa1 = (const float*)d_in[2];
    const float* ba1 = (const float*)d_in[3];
    const float* wa2 = (const float*)d_in[4];
    const float* Wl  = (const float*)d_in[5];
    const float* bl  = (const float*)d_in[6];
    float* out = (float*)d_out;

    char* ws = (char*)d_ws;
    unsigned short* WyS  = (unsigned short*)(ws);                     // 512 KB
    unsigned short* WiS  = (unsigned short*)(ws + 524288);            // 512 KB
    unsigned short* WaS  = (unsigned short*)(ws + 1048576);           // 512 KB
    float*          ixf  = (float*)(ws + 1572864);                    // 2 MB (1024 rows)
    unsigned short* ixb  = (unsigned short*)(ws + 3670016);           // 1 MB (1024 rows)
    float*          ipre = (float*)(ws + 4718592);                    // 2 MB (1024 rows)

    hipLaunchKernelGGL(prep_kernel, dim3(384), dim3(256), 0, stream, Wa1, Wl, WyS, WiS, WaS);
    hipLaunchKernelGGL(attn_pool_kernel, dim3(1016), dim3(256), 0, stream,
                       x, WaS, ba1, wa2, ixf, ixb);
    hipLaunchKernelGGL(ipre_kernel, dim3(64, 4), dim3(256), 0, stream, ixb, WiS, bl, ipre);
    hipLaunchKernelGGL(main_kernel, dim3(524), dim3(512), 0, stream,
                       y, WyS, ixf, ipre, out);
}

// Round 13
// 152.239 us; speedup vs baseline: 1.0511x; 1.0511x over previous
//
#include <hip/hip_runtime.h>
#include <cstdint>
#include <cstddef>

#define H 512
#define SEQ 128

typedef __bf16 v8bf __attribute__((ext_vector_type(8)));
typedef float v4f __attribute__((ext_vector_type(4)));
typedef unsigned short v8us __attribute__((ext_vector_type(8)));

__device__ __forceinline__ unsigned short f2bf(float f) {
    unsigned int u = __float_as_uint(f);
    u = (u + 0x7FFFu + ((u >> 16) & 1u)) >> 16;
    return (unsigned short)u;
}
__device__ __forceinline__ float bf2f(unsigned short h) {
    return __uint_as_float(((unsigned int)h) << 16);
}
__device__ __forceinline__ v8bf load_bf8(const unsigned short* p) {
    return *reinterpret_cast<const v8bf*>(p);
}
__device__ __forceinline__ float fast_tanh(float v) {
    float e = __expf(2.f * v);
    return 1.f - 2.f * __builtin_amdgcn_rcpf(e + 1.f);
}
__device__ __forceinline__ float fast_sigmoid(float v) {
    return __builtin_amdgcn_rcpf(1.f + __expf(-v));
}
__device__ __forceinline__ v8us cvt8u(float4 lo, float4 hi) {
    v8us r;
    r[0] = f2bf(lo.x); r[1] = f2bf(lo.y); r[2] = f2bf(lo.z); r[3] = f2bf(lo.w);
    r[4] = f2bf(hi.x); r[5] = f2bf(hi.y); r[6] = f2bf(hi.z); r[7] = f2bf(hi.w);
    return r;
}
// async global->LDS, 16B/lane; LDS dest = wave-uniform base + lane*16.
__device__ __forceinline__ void gll16(const unsigned short* g, unsigned short* l) {
    __builtin_amdgcn_global_load_lds(
        (const __attribute__((address_space(1))) unsigned int*)g,
        (__attribute__((address_space(3))) unsigned int*)l, 16, 0, 0);
}

// Swizzled B layout: frag[((c*16 + ks)*64 + lane)*8 + j] = W[g][k]
//   g = c*16 + (lane&15),  k = ks*32 + (lane>>4)*8 + j

// ---------------------------------------------------------------------------
// prep: build swizzled WyS (Wl[:, :512]), WiS (Wl[:, 512:]), WaS (Wa1^T)
// ---------------------------------------------------------------------------
__global__ __launch_bounds__(256) void prep_kernel(
        const float* __restrict__ Wa1, const float* __restrict__ Wl,
        unsigned short* __restrict__ WyS, unsigned short* __restrict__ WiS,
        unsigned short* __restrict__ WaS) {
    int tg = blockIdx.x * 256 + threadIdx.x;   // 0..98303
    int mat = tg >> 15;
    int idx = tg & 32767;
    int lane = idx & 63;
    int ks = (idx >> 6) & 15;
    int c = idx >> 10;
    int g = c * 16 + (lane & 15);
    int hb = ks * 32 + ((lane >> 4) << 3);
    unsigned short o[8];
    unsigned short* dst;
    if (mat == 0) {
        const float* s = Wl + (size_t)g * 1024 + hb;
#pragma unroll
        for (int j = 0; j < 8; ++j) o[j] = f2bf(s[j]);
        dst = WyS + (size_t)idx * 8;
    } else if (mat == 1) {
        const float* s = Wl + (size_t)g * 1024 + 512 + hb;
#pragma unroll
        for (int j = 0; j < 8; ++j) o[j] = f2bf(s[j]);
        dst = WiS + (size_t)idx * 8;
    } else {
#pragma unroll
        for (int j = 0; j < 8; ++j) o[j] = f2bf(Wa1[(size_t)(hb + j) * H + g]);
        dst = WaS + (size_t)idx * 8;
    }
    *reinterpret_cast<ushort4*>(dst)     = *reinterpret_cast<ushort4*>(&o[0]);
    *reinterpret_cast<ushort4*>(dst + 4) = *reinterpret_cast<ushort4*>(&o[4]);
}

// ---------------------------------------------------------------------------
// attn_pool: one block per (b, s<127).  wave = 32 rows x 128 cols, acc 2x8.
// ---------------------------------------------------------------------------
__global__ __launch_bounds__(256, 4) void attn_pool_kernel(
        const float* __restrict__ x, const unsigned short* __restrict__ WaS,
        const float* __restrict__ ba1, const float* __restrict__ wa2,
        float* __restrict__ ixf, unsigned short* __restrict__ ixb) {
    __shared__ __align__(16) unsigned short Xb[32][520];
    __shared__ float attn[32];
    __shared__ float scpart[4][32];

    int bid = blockIdx.x;
    int b = bid / 127, s = bid % 127;
    int t = threadIdx.x;

    const float4* x4 = reinterpret_cast<const float4*>(x + (size_t)(b * SEQ + s) * 32 * H);
#pragma unroll
    for (int i = 0; i < 16; ++i) {
        int idx4 = t + i * 256;
        float4 v = x4[idx4];
        int e = idx4 * 4, m = e >> 9, h = e & 511;
        ushort4 o;
        o.x = f2bf(v.x); o.y = f2bf(v.y); o.z = f2bf(v.z); o.w = f2bf(v.w);
        *reinterpret_cast<ushort4*>(&Xb[m][h]) = o;
    }
    __syncthreads();

    int w = t >> 6, lane = t & 63, q = lane >> 4, c16 = lane & 15;

    v4f acc[2][8];
#pragma unroll
    for (int mi = 0; mi < 2; ++mi)
#pragma unroll
        for (int ci = 0; ci < 8; ++ci) acc[mi][ci] = (v4f){0.f, 0.f, 0.f, 0.f};

    const unsigned short* Bb = WaS + (size_t)(w * 8 * 16) * 512 + lane * 8;

#pragma unroll
    for (int ks = 0; ks < 16; ++ks) {
        v8bf a0 = load_bf8(&Xb[c16][ks * 32 + q * 8]);
        v8bf a1 = load_bf8(&Xb[16 + c16][ks * 32 + q * 8]);
#pragma unroll
        for (int ci = 0; ci < 8; ++ci) {
            v8bf bb = load_bf8(Bb + (size_t)(ci * 16 + ks) * 512);
            acc[0][ci] = __builtin_amdgcn_mfma_f32_16x16x32_bf16(a0, bb, acc[0][ci], 0, 0, 0);
            acc[1][ci] = __builtin_amdgcn_mfma_f32_16x16x32_bf16(a1, bb, acc[1][ci], 0, 0, 0);
        }
    }

    float sr[2][4] = {{0.f, 0.f, 0.f, 0.f}, {0.f, 0.f, 0.f, 0.f}};
#pragma unroll
    for (int ci = 0; ci < 8; ++ci) {
        int g = (w * 8 + ci) * 16 + c16;
        float w2 = wa2[g];
        float bv = ba1[g];
#pragma unroll
        for (int mi = 0; mi < 2; ++mi)
#pragma unroll
            for (int i = 0; i < 4; ++i)
                sr[mi][i] += w2 * fast_tanh(acc[mi][ci][i] + bv);
    }
#pragma unroll
    for (int off = 1; off < 16; off <<= 1) {
#pragma unroll
        for (int mi = 0; mi < 2; ++mi)
#pragma unroll
            for (int i = 0; i < 4; ++i) sr[mi][i] += __shfl_xor(sr[mi][i], off);
    }
    if (c16 == 0) {
#pragma unroll
        for (int mi = 0; mi < 2; ++mi)
#pragma unroll
            for (int i = 0; i < 4; ++i) scpart[w][mi * 16 + q * 4 + i] = sr[mi][i];
    }
    __syncthreads();

    if (t < 64) {
        int m = t & 31;
        float v = scpart[0][m] + scpart[1][m] + scpart[2][m] + scpart[3][m];
        float mx = v;
#pragma unroll
        for (int off = 1; off < 32; off <<= 1) mx = fmaxf(mx, __shfl_xor(mx, off));
        float e = __expf(v - mx);
        float sum = e;
#pragma unroll
        for (int off = 1; off < 32; off <<= 1) sum += __shfl_xor(sum, off);
        if (t < 32) attn[m] = e * __builtin_amdgcn_rcpf(sum);
    }
    __syncthreads();

    int h0 = t * 2;
    float p0 = 0.f, p1 = 0.f;
#pragma unroll
    for (int m = 0; m < 32; ++m) {
        float am = attn[m];
        p0 += am * bf2f(Xb[m][h0]);
        p1 += am * bf2f(Xb[m][h0 + 1]);
    }
    size_t r = (size_t)bid;
    ixf[r * H + h0] = p0;
    ixf[r * H + h0 + 1] = p1;
    ixb[r * H + h0] = f2bf(p0);
    ixb[r * H + h0 + 1] = f2bf(p1);
}

// ---------------------------------------------------------------------------
// ipre: i_pre[r,g] = sum_h i_x[r,h] * Wi[g,h] + bl[g]   (r < 1016)
// ---------------------------------------------------------------------------
__global__ __launch_bounds__(256) void ipre_kernel(
        const unsigned short* __restrict__ ixb, const unsigned short* __restrict__ WiS,
        const float* __restrict__ bl, float* __restrict__ ipre) {
    int row16 = blockIdx.x * 16;
    int t = threadIdx.x, w = t >> 6, lane = t & 63, q = lane >> 4, c16 = lane & 15;
    int c0 = blockIdx.y * 8 + w * 2;

    v4f acc0 = {0.f, 0.f, 0.f, 0.f};
    v4f acc1 = {0.f, 0.f, 0.f, 0.f};
    const unsigned short* arow = ixb + (size_t)(row16 + c16) * H + q * 8;
#pragma unroll
    for (int ks = 0; ks < 16; ++ks) {
        v8bf a = load_bf8(arow + ks * 32);
        acc0 = __builtin_amdgcn_mfma_f32_16x16x32_bf16(
            a, load_bf8(WiS + (size_t)(c0 * 16 + ks) * 512 + lane * 8), acc0, 0, 0, 0);
        acc1 = __builtin_amdgcn_mfma_f32_16x16x32_bf16(
            a, load_bf8(WiS + (size_t)((c0 + 1) * 16 + ks) * 512 + lane * 8), acc1, 0, 0, 0);
    }
#pragma unroll
    for (int cc = 0; cc < 2; ++cc) {
        int g = (c0 + cc) * 16 + c16;
        float blv = bl[g];
        v4f a = cc ? acc1 : acc0;
#pragma unroll
        for (int i = 0; i < 4; ++i) {
            int row = row16 + q * 4 + i;
            if (row < 1016) ipre[(size_t)row * H + g] = a[i] + blv;
        }
    }
}

// ---------------------------------------------------------------------------
// main v13: r12 structure with SAFE __syncthreads (r12's counted-vmcnt raced:
// issue order unpinnable in plain HIP; prologue lacked vmcnt drain for gll).
// 64 rows x 256 cols per block (2032 GEMM blocks), 256 thr, 4 waves,
// wave = 32x128, acc[2][8]=64 AGPR.
//   - B: global_load_lds (L2-resident WyS, no VGPR round-trip)
//   - A: reg-staged, issued 2 phases early (1 full phase of latency cover
//     even with the __syncthreads vmcnt drain)
// XCD-contiguous swizzle (2032 = 8*254).  LDS 44 KB -> 3 blocks/CU.
// Coalesced LDS epilogue (2 slabs of 32 rows).
// ---------------------------------------------------------------------------
__global__ __launch_bounds__(256, 3) void main_kernel(
        const float* __restrict__ y, const unsigned short* __restrict__ WyS,
        const float* __restrict__ ixf, const float* __restrict__ ipre,
        float* __restrict__ out) {
    int bid0 = blockIdx.x;
    int t = threadIdx.x;

    if (bid0 >= 2032) {
        // s==0 passthrough: 16 blocks, each copies 32 rows x 512 cols f32.
        int cb = bid0 - 2032;            // 0..15
        int b = cb >> 1, half = cb & 1;
        size_t base = ((size_t)(b * SEQ)) * 64 * H + (size_t)half * 32 * H;
        const float4* y4 = reinterpret_cast<const float4*>(y + base);
        float4* o4 = reinterpret_cast<float4*>(out + base);
#pragma unroll
        for (int i = 0; i < 16; ++i) o4[t + i * 256] = y4[t + i * 256];
        return;
    }

    // XCD-contiguous swizzle: 2032 = 8 * 254 (exact)
    int bid = (bid0 & 7) * 254 + (bid0 >> 3);
    int rg = bid >> 1;                   // tile 0..1015 (one 64-row (b,s) tile)
    int ch = bid & 1;                    // col half: g in [ch*256, ch*256+256)

    __shared__ __align__(16) char arena[45056];
    unsigned short* As = (unsigned short*)arena;             // [2][64*40] = 10240 B
    unsigned short* Bs = (unsigned short*)(arena + 10240);   // [2][16*512] = 32768 B
    float* ip_s = (float*)(arena + 43008);                   // [256]
    float* ix_s = (float*)(arena + 44032);                   // [256]
    float* ep   = (float*)arena;                             // epilogue alias [32][260]

    int b0 = rg / 127, s0 = rg % 127;
    size_t obase = ((size_t)(b0 * SEQ + s0 + 1) * 64) * H;

    int w = t >> 6, lane = t & 63, q = lane >> 4, c16 = lane & 15;
    int wr = w >> 1, wc = w & 1;

    // A staging: thread -> row t>>2 (0..63), 8 f32 at col (t&3)*8 per phase
    int arow = t >> 2;
    int acol = (t & 3) * 8;
    const float* ysrc = y + obase + (size_t)arow * H + acol;

    // B staging: wave w stages frags w*4..w*4+3; per-lane global source
    const unsigned short* bbase = WyS + ((size_t)((ch * 16 + w * 4) * 16)) * 512 + lane * 8;

    // ip/ix staging (256 cols, once)
    {
        size_t rr = (size_t)rg * H + ch * 256 + t;
        ip_s[t] = ipre[rr];
        ix_s[t] = ixf[rr];
    }

    // ---- prologue: B(0) async; A(0),A(1) issued; A(0) written ----
#pragma unroll
    for (int j = 0; j < 4; ++j)
        gll16(bbase + (size_t)j * 8192, &Bs[(w * 4 + j) * 512]);
    float4 alo[2], ahi[2];               // set k holds A(q), q&1==k
    alo[0] = *reinterpret_cast<const float4*>(ysrc);
    ahi[0] = *reinterpret_cast<const float4*>(ysrc + 4);
    alo[1] = *reinterpret_cast<const float4*>(ysrc + 32);
    ahi[1] = *reinterpret_cast<const float4*>(ysrc + 36);
    *reinterpret_cast<v8us*>(&As[arow * 40 + acol]) = cvt8u(alo[0], ahi[0]);
    __syncthreads();   // drains vmcnt (gll B(0)) + lgkmcnt (A(0) LDS writes)

    v4f acc[2][8];
#pragma unroll
    for (int rt = 0; rt < 2; ++rt)
#pragma unroll
        for (int ci = 0; ci < 8; ++ci) acc[rt][ci] = (v4f){0.f, 0.f, 0.f, 0.f};

    // ---- K loop: 16 phases, dbuf, issue-early, safe barriers ----
#pragma unroll
    for (int p = 0; p < 16; ++p) {
        const int buf = p & 1;
        const int nxt = buf ^ 1;
        if (p < 15) {
            // async B(p+1) -> other buffer (source is L2-resident)
#pragma unroll
            for (int j = 0; j < 4; ++j)
                gll16(bbase + (size_t)j * 8192 + (size_t)(p + 1) * 512,
                      &Bs[nxt * 8192 + (w * 4 + j) * 512]);
        }
        if (p < 14) {
            // issue A(p+2) into set (p&1)  [(p+2)&1 == p&1]
            alo[buf] = *reinterpret_cast<const float4*>(ysrc + (p + 2) * 32);
            ahi[buf] = *reinterpret_cast<const float4*>(ysrc + (p + 2) * 32 + 4);
        }
        if (p < 15) {
            // write A(p+1) (set nxt) -> LDS buffer nxt
            *reinterpret_cast<v8us*>(&As[nxt * 2560 + arow * 40 + acol]) =
                cvt8u(alo[nxt], ahi[nxt]);
        }

        v8bf af0 = load_bf8(&As[buf * 2560 + (wr * 32 + c16) * 40 + q * 8]);
        v8bf af1 = load_bf8(&As[buf * 2560 + (wr * 32 + 16 + c16) * 40 + q * 8]);
#pragma unroll
        for (int ci = 0; ci < 8; ++ci) {
            v8bf bfc = load_bf8(&Bs[buf * 8192 + (wc * 8 + ci) * 512 + lane * 8]);
            acc[0][ci] = __builtin_amdgcn_mfma_f32_16x16x32_bf16(af0, bfc, acc[0][ci], 0, 0, 0);
            acc[1][ci] = __builtin_amdgcn_mfma_f32_16x16x32_bf16(af1, bfc, acc[1][ci], 0, 0, 0);
        }

        if (p < 15) __syncthreads();   // safe: drains vmcnt+lgkmcnt for dbuf
    }

    // ---- coalesced epilogue via LDS, 2 slabs of 32 rows ----
#pragma unroll
    for (int s = 0; s < 2; ++s) {
        __syncthreads();   // s=0: also retires As/Bs (aliased by ep)
        if (wr == s) {
#pragma unroll
            for (int ci = 0; ci < 8; ++ci) {
                int gl = wc * 128 + ci * 16 + c16;        // 0..255
                float ipv = ip_s[gl];
                float ixv = ix_s[gl];
#pragma unroll
                for (int rt = 0; rt < 2; ++rt)
#pragma unroll
                    for (int i = 0; i < 4; ++i) {
                        int rl = rt * 16 + q * 4 + i;     // 0..31 within slab
                        ep[rl * 260 + gl] = ixv * fast_sigmoid(acc[rt][ci][i] + ipv);
                    }
            }
        }
        __syncthreads();
        // cooperative coalesced store: 32 rows x 256 f32 = 2048 float4
#pragma unroll
        for (int k = 0; k < 8; ++k) {
            int c = t + k * 256;                  // 0..2047
            int rl = c >> 6;                      // 0..31
            int cx = (c & 63) * 4;                // f32 col within 256
            int n = s * 32 + rl;                  // row within tile
            size_t off = obase + (size_t)n * H + ch * 256 + cx;
            float4 g4 = *reinterpret_cast<const float4*>(&ep[rl * 260 + cx]);
            float4 yv = *reinterpret_cast<const float4*>(&y[off]);
            float4 o;
            o.x = yv.x + g4.x; o.y = yv.y + g4.y;
            o.z = yv.z + g4.z; o.w = yv.w + g4.w;
            *reinterpret_cast<float4*>(&out[off]) = o;
        }
    }
}

// ---------------------------------------------------------------------------
extern "C" void kernel_launch(void* const* d_in, const int* in_sizes, int n_in,
                              void* d_out, int out_size, void* d_ws, size_t ws_size,
                              hipStream_t stream) {
    const float* x   = (const float*)d_in[0];
    const float* y   = (const float*)d_in[1];
    const float* Wa1 = (const float*)d_in[2];
    const float* ba1 = (const float*)d_in[3];
    const float* wa2 = (const float*)d_in[4];
    const float* Wl  = (const float*)d_in[5];
    const float* bl  = (const float*)d_in[6];
    float* out = (float*)d_out;

    char* ws = (char*)d_ws;
    unsigned short* WyS  = (unsigned short*)(ws);                     // 512 KB
    unsigned short* WiS  = (unsigned short*)(ws + 524288);            // 512 KB
    unsigned short* WaS  = (unsigned short*)(ws + 1048576);           // 512 KB
    float*          ixf  = (float*)(ws + 1572864);                    // 2 MB (1024 rows)
    unsigned short* ixb  = (unsigned short*)(ws + 3670016);           // 1 MB (1024 rows)
    float*          ipre = (float*)(ws + 4718592);                    // 2 MB (1024 rows)

    hipLaunchKernelGGL(prep_kernel, dim3(384), dim3(256), 0, stream, Wa1, Wl, WyS, WiS, WaS);
    hipLaunchKernelGGL(attn_pool_kernel, dim3(1016), dim3(256), 0, stream,
                       x, WaS, ba1, wa2, ixf, ixb);
    hipLaunchKernelGGL(ipre_kernel, dim3(64, 4), dim3(256), 0, stream, ixb, WiS, bl, ipre);
    hipLaunchKernelGGL(main_kernel, dim3(2048), dim3(256), 0, stream,
                       y, WyS, ixf, ipre, out);
}